// Round 8
// baseline (81.894 us; speedup 1.0000x reference)
//
#include <hip/hip_runtime.h>

#define SEQ  2048
#define DIM  1024
#define HD   64
#define CT   2                 // key tiles per chunk (128 keys)
#define MAXCH 16

typedef float f32x4  __attribute__((ext_vector_type(4)));
typedef short bf16x8 __attribute__((ext_vector_type(8)));

__device__ __forceinline__ short f2bf(float x) {          // RNE
    union { float f; unsigned u; } v; v.f = x;
    unsigned r = v.u + 0x7FFFu + ((v.u >> 16) & 1u);
    return (short)(r >> 16);
}
__device__ __forceinline__ short f2bf_fast(float x) {     // round-half-up
    union { float f; unsigned u; } v; v.f = x;
    return (short)((v.u + 0x8000u) >> 16);
}

#define MFMA16(a, b, c) __builtin_amdgcn_mfma_f32_16x16x32_bf16((a), (b), (c), 0, 0, 0)

// ---------------------------------------------------------------------------
// wprep: repack Wq/Wk/Wv (fp32 [1024][64]) into bf16 MFMA B-fragment order:
// wfrag[which][kstep 32][nfrag 4][lane 64][8].
// ---------------------------------------------------------------------------
__global__ __launch_bounds__(256) void wprep_kernel(
    const float* __restrict__ Wq, const float* __restrict__ Wk,
    const float* __restrict__ Wv, short* __restrict__ wfrag)
{
    const int idx = blockIdx.x * 256 + threadIdx.x;   // 0..24575
    const int l  = idx & 63;
    const int n  = (idx >> 6) & 3;
    const int ks = (idx >> 8) & 31;
    const int w  = idx >> 13;
    const float* __restrict__ W = (w == 0) ? Wq : (w == 1) ? Wk : Wv;
    bf16x8 v;
#pragma unroll
    for (int j = 0; j < 8; ++j)
        v[j] = f2bf(W[(size_t)(ks * 32 + (l >> 4) * 8 + j) * HD + n * 16 + (l & 15)]);
    *reinterpret_cast<bf16x8*>(wfrag + (size_t)idx * 8) = v;
}

// ---------------------------------------------------------------------------
// proj: grid 512, block 256 (4 waves).  Block = one 16-row tile of ALL THREE
// outputs; waves split K 4-ways (8 ks-iters each); f32x4 LDS reduction;
// wave 0 -> Q (x0.125), 1 -> K, 2 -> Vt (transposed).  x read exactly once.
// ---------------------------------------------------------------------------
__global__ __launch_bounds__(256) void proj_kernel(
    const float* __restrict__ x, const short* __restrict__ wfrag,
    const float* __restrict__ bq, const float* __restrict__ bk,
    const float* __restrict__ bv,
    short* __restrict__ Qs, short* __restrict__ Kb, short* __restrict__ Vt)
{
    __shared__ __align__(16) char smem[49152 + 2304];

    const int tid  = threadIdx.x;
    const int lane = tid & 63;
    const int w    = tid >> 6;
    const int c    = lane & 15;
    const int g    = lane >> 4;
    const int r0   = blockIdx.x * 16;

    f32x4 acc[3][4] = {};
    for (int ks = w * 8; ks < w * 8 + 8; ++ks) {
        const float* xp = x + (size_t)(r0 + c) * DIM + ks * 32 + g * 8;
        float4 a0 = *reinterpret_cast<const float4*>(xp);
        float4 a1 = *reinterpret_cast<const float4*>(xp + 4);
        float av[8] = {a0.x, a0.y, a0.z, a0.w, a1.x, a1.y, a1.z, a1.w};
        bf16x8 af;
#pragma unroll
        for (int j = 0; j < 8; ++j) af[j] = f2bf_fast(av[j]);
#pragma unroll
        for (int which = 0; which < 3; ++which)
#pragma unroll
            for (int n = 0; n < 4; ++n) {
                bf16x8 bfr = *reinterpret_cast<const bf16x8*>(
                    wfrag + ((size_t)((which * 32 + ks) * 4 + n) * 64 + lane) * 8);
                acc[which][n] = MFMA16(af, bfr, acc[which][n]);
            }
    }

    f32x4* red = (f32x4*)smem;   // [chunk 12][wave 4][lane 64]
#pragma unroll
    for (int which = 0; which < 3; ++which)
#pragma unroll
        for (int n = 0; n < 4; ++n)
            red[((which * 4 + n) * 4 + w) * 64 + lane] = acc[which][n];
    __syncthreads();

    if (w < 3) {
        const float* __restrict__ bias = (w == 0) ? bq : (w == 1) ? bk : bv;
        f32x4 sum[4];
#pragma unroll
        for (int n = 0; n < 4; ++n) {
            sum[n] = red[((w * 4 + n) * 4 + 0) * 64 + lane];
#pragma unroll
            for (int s = 1; s < 4; ++s)
                sum[n] += red[((w * 4 + n) * 4 + s) * 64 + lane];
        }
        if (w < 2) {
            short* __restrict__ o = (w == 0) ? Qs : Kb;
            const float sc = (w == 0) ? 0.125f : 1.0f;
#pragma unroll
            for (int n = 0; n < 4; ++n) {
                const float bb = bias[n * 16 + c];
#pragma unroll
                for (int i = 0; i < 4; ++i)
                    o[(size_t)(r0 + g * 4 + i) * HD + n * 16 + c] =
                        f2bf((sum[n][i] + bb) * sc);
            }
        } else {
            short* ts = (short*)(smem + 49152);    // [16][72]
#pragma unroll
            for (int n = 0; n < 4; ++n) {
                const float bb = bias[n * 16 + c];
#pragma unroll
                for (int i = 0; i < 4; ++i)
                    ts[(g * 4 + i) * 72 + n * 16 + c] = f2bf(sum[n][i] + bb);
            }
            // same-wave LDS RAW: compiler inserts lgkmcnt wait
            bf16x8 o0, o1;
#pragma unroll
            for (int e = 0; e < 8; ++e) o0[e] = ts[e * 72 + lane];
#pragma unroll
            for (int e = 0; e < 8; ++e) o1[e] = ts[(8 + e) * 72 + lane];
            const int b  = r0 >> 11;
            const int sb = r0 & (SEQ - 1);
            short* dst = Vt + (((size_t)(b * 64 + lane)) << 11) + sb;
            *reinterpret_cast<bf16x8*>(dst)     = o0;
            *reinterpret_cast<bf16x8*>(dst + 8) = o1;
        }
    }
}

// ===========================================================================
// attn: split-key partials, CT=2 (128 keys/unit).  Exactly 4352 active units
// on 1088 blocks x 4 waves (no empties).  Per batch (1088 units): group
// g' (=qloc/8, 0..15) has 8 q-tiles x (g'+1) chunks; offset C(g')=4g'(g'+1).
// Unit = (q-tile, chunk): QK MFMAs for <=2 key tiles, ONE exact softmax,
// P->LDS, PV MFMAs, write unnormalized partials.  NO fences, NO atomics.
// ===========================================================================
__global__ __launch_bounds__(256) void attn_kernel(
    const short* __restrict__ Qs, const short* __restrict__ Kb,
    const short* __restrict__ Vt, float* __restrict__ Opart,
    float2* __restrict__ mlpart)
{
    __shared__ short P_all[4][16 * 136];

    const int tid  = threadIdx.x;
    const int lane = tid & 63;
    const int w    = tid >> 6;
    const int c    = lane & 15;
    const int g    = lane >> 4;

    const int u     = blockIdx.x * 4 + w;       // 0..4351
    const int batch = u / 1088;
    const int up    = u - batch * 1088;
    int grp = 0;
#pragma unroll
    for (int t = 1; t < 16; ++t) if (up >= 4 * t * (t + 1)) grp = t;
    const int r    = up - 4 * grp * (grp + 1);
    const int qloc = grp * 8 + (r & 7);
    const int cid  = r >> 3;                    // 0..grp
    const int qb   = batch * 128 + qloc;
    const int q0g  = qb * 16;
    const int qbase = qloc * 16;
    const int tlast = qloc >> 2;
    const int t0    = cid * CT;
    const int nact  = min(CT, tlast - t0 + 1);

    short* P = P_all[w];

    bf16x8 qf[2];
    qf[0] = *reinterpret_cast<const bf16x8*>(Qs + (size_t)(q0g + c) * HD + g * 8);
    qf[1] = *reinterpret_cast<const bf16x8*>(Qs + (size_t)(q0g + c) * HD + 32 + g * 8);

    const size_t krow0 = (size_t)batch * SEQ;

    // ---- Phase 1: QK^T for active tiles ----
    f32x4 S[CT][4] = {};
#pragma unroll
    for (int tt = 0; tt < CT; ++tt) {
        if (tt >= nact) continue;               // wave-uniform
        const int key0 = (t0 + tt) * 64;
        bf16x8 kf[4][2];
#pragma unroll
        for (int n = 0; n < 4; ++n)
#pragma unroll
            for (int st = 0; st < 2; ++st)
                kf[n][st] = *reinterpret_cast<const bf16x8*>(
                    Kb + (krow0 + key0 + n * 16 + c) * HD + st * 32 + g * 8);
#pragma unroll
        for (int st = 0; st < 2; ++st)
#pragma unroll
            for (int n = 0; n < 4; ++n)
                S[tt][n] = MFMA16(qf[st], kf[n][st], S[tt][n]);
    }

    // causal mask: only diagonal tile
    if (tlast - t0 < CT) {
        const int ttd  = tlast - t0;
        const int key0 = tlast * 64;
#pragma unroll
        for (int tt = 0; tt < CT; ++tt) {
            if (tt != ttd) continue;
#pragma unroll
            for (int n = 0; n < 4; ++n)
#pragma unroll
                for (int i = 0; i < 4; ++i)
                    if (key0 + n * 16 + c > qbase + g * 4 + i)
                        S[tt][n][i] = -__builtin_inff();
        }
    }

    // ---- Phase 2: one exact softmax over the chunk ----
    float mx[4], rs[4];
#pragma unroll
    for (int i = 0; i < 4; ++i) { mx[i] = -__builtin_inff(); rs[i] = 0.f; }
#pragma unroll
    for (int tt = 0; tt < CT; ++tt) {
        if (tt >= nact) continue;
#pragma unroll
        for (int n = 0; n < 4; ++n)
#pragma unroll
            for (int i = 0; i < 4; ++i)
                mx[i] = fmaxf(mx[i], S[tt][n][i]);
    }
#pragma unroll
    for (int off = 1; off <= 8; off <<= 1)
#pragma unroll
        for (int i = 0; i < 4; ++i)
            mx[i] = fmaxf(mx[i], __shfl_xor(mx[i], off, 64));
#pragma unroll
    for (int tt = 0; tt < CT; ++tt) {
        if (tt >= nact) continue;
#pragma unroll
        for (int n = 0; n < 4; ++n)
#pragma unroll
            for (int i = 0; i < 4; ++i) {
                const float p = __expf(S[tt][n][i] - mx[i]);
                S[tt][n][i] = p;
                rs[i] += p;
            }
    }
#pragma unroll
    for (int off = 1; off <= 8; off <<= 1)
#pragma unroll
        for (int i = 0; i < 4; ++i)
            rs[i] += __shfl_xor(rs[i], off, 64);

    // ---- Phase 3: P -> LDS, PV ----
#pragma unroll
    for (int tt = 0; tt < CT; ++tt) {
        if (tt >= nact) continue;
#pragma unroll
        for (int n = 0; n < 4; ++n)
#pragma unroll
            for (int i = 0; i < 4; ++i)
                P[(g * 4 + i) * 136 + tt * 64 + n * 16 + c] = f2bf_fast(S[tt][n][i]);
    }
    // same-wave LDS RAW: compiler inserts lgkmcnt wait

    f32x4 O[4] = {};
#pragma unroll
    for (int tt = 0; tt < CT; ++tt) {
        if (tt >= nact) continue;
        const int key0 = (t0 + tt) * 64;
#pragma unroll
        for (int st = 0; st < 2; ++st) {
            bf16x8 pf = *reinterpret_cast<const bf16x8*>(
                &P[c * 136 + tt * 64 + st * 32 + g * 8]);
#pragma unroll
            for (int n = 0; n < 4; ++n) {
                bf16x8 vf = *reinterpret_cast<const bf16x8*>(
                    Vt + (((size_t)(batch * 64 + n * 16 + c)) << 11) + key0 + st * 32 + g * 8);
                O[n] = MFMA16(pf, vf, O[n]);
            }
        }
    }

    // ---- write partials ----
    float* op = Opart + ((size_t)(qb * MAXCH + cid) * 16) * 64;
#pragma unroll
    for (int n = 0; n < 4; ++n)
#pragma unroll
        for (int i = 0; i < 4; ++i)
            op[(size_t)(g * 4 + i) * 64 + n * 16 + c] = O[n][i];
    if (c == 0) {
#pragma unroll
        for (int i = 0; i < 4; ++i)
            mlpart[(size_t)(qb * MAXCH + cid) * 16 + g * 4 + i] =
                make_float2(mx[i], rs[i]);
    }
}

// ---------------------------------------------------------------------------
// combine: grid = 512, block = 256 (4 waves; wave w handles rows w*4..w*4+3).
// ---------------------------------------------------------------------------
__global__ __launch_bounds__(256) void attn_combine_kernel(
    const float* __restrict__ Opart, const float2* __restrict__ mlpart,
    float* __restrict__ out)
{
    const int qb = blockIdx.x;
    const int d  = threadIdx.x & 63;
    const int w  = threadIdx.x >> 6;
    const int qbase = (qb * 16) & (SEQ - 1);
    const int NC = (qbase >> 6) / CT + 1;

#pragma unroll
    for (int ri = 0; ri < 4; ++ri) {
        const int r = w * 4 + ri;
        float m = -__builtin_inff();
        for (int ci = 0; ci < NC; ++ci)
            m = fmaxf(m, mlpart[(size_t)(qb * MAXCH + ci) * 16 + r].x);
        float l = 0.f, o = 0.f;
        for (int ci = 0; ci < NC; ++ci) {
            const float2 ml = mlpart[(size_t)(qb * MAXCH + ci) * 16 + r];
            const float wgt = __expf(ml.x - m);
            l += wgt * ml.y;
            o += wgt * Opart[((size_t)(qb * MAXCH + ci) * 16 + r) * 64 + d];
        }
        out[(size_t)(qb * 16 + r) * HD + d] = o / l;
    }
}

// ---------------------------------------------------------------------------
extern "C" void kernel_launch(void* const* d_in, const int* in_sizes, int n_in,
                              void* d_out, int out_size, void* d_ws, size_t ws_size,
                              hipStream_t stream)
{
    (void)in_sizes; (void)n_in; (void)out_size; (void)ws_size;
    const float* x  = (const float*)d_in[0];
    const float* Wq = (const float*)d_in[1];
    const float* bq = (const float*)d_in[2];
    const float* Wk = (const float*)d_in[3];
    const float* bk = (const float*)d_in[4];
    const float* Wv = (const float*)d_in[5];
    const float* bv = (const float*)d_in[6];
    float* out = (float*)d_out;

    char* ws = (char*)d_ws;
    short*  Qs     = (short*)(ws);                  // 1 MB
    short*  Kb     = (short*)(ws + (1u << 20));     // 1 MB
    short*  Vt     = (short*)(ws + (2u << 20));     // 1 MB  [4][64][2048]
    short*  wfrag  = (short*)(ws + (3u << 20));     // 384 KB
    float*  Opart  = (float*)(ws + (4u << 20));     // 32 MB
    float2* mlpart = (float2*)(ws + (36u << 20));   // 1 MB

    wprep_kernel<<<96, 256, 0, stream>>>(Wq, Wk, Wv, wfrag);
    proj_kernel<<<512, 256, 0, stream>>>(x, wfrag, bq, bk, bv, Qs, Kb, Vt);
    attn_kernel<<<1088, 256, 0, stream>>>(Qs, Kb, Vt, Opart, mlpart);
    attn_combine_kernel<<<512, 256, 0, stream>>>(Opart, mlpart, out);
}

// Round 9
// 47.466 us; speedup vs baseline: 1.7253x; 1.7253x over previous
//
#include <hip/hip_runtime.h>

#define SEQ  2048
#define DIM  1024
#define HD   64

typedef float f32x4  __attribute__((ext_vector_type(4)));
typedef short bf16x8 __attribute__((ext_vector_type(8)));

__device__ __forceinline__ short f2bf(float x) {          // RNE
    union { float f; unsigned u; } v; v.f = x;
    unsigned r = v.u + 0x7FFFu + ((v.u >> 16) & 1u);
    return (short)(r >> 16);
}
__device__ __forceinline__ short f2bf_fast(float x) {     // round-half-up
    union { float f; unsigned u; } v; v.f = x;
    return (short)((v.u + 0x8000u) >> 16);
}

#define MFMA16(a, b, c) __builtin_amdgcn_mfma_f32_16x16x32_bf16((a), (b), (c), 0, 0, 0)

// ---------------------------------------------------------------------------
// wprep: repack Wq/Wk/Wv (fp32 [1024][64]) into bf16 MFMA B-fragment order:
// wfrag[which][kstep 32][nfrag 4][lane 64][8].
// ---------------------------------------------------------------------------
__global__ __launch_bounds__(256) void wprep_kernel(
    const float* __restrict__ Wq, const float* __restrict__ Wk,
    const float* __restrict__ Wv, short* __restrict__ wfrag)
{
    const int idx = blockIdx.x * 256 + threadIdx.x;   // 0..24575
    const int l  = idx & 63;
    const int n  = (idx >> 6) & 3;
    const int ks = (idx >> 8) & 31;
    const int w  = idx >> 13;
    const float* __restrict__ W = (w == 0) ? Wq : (w == 1) ? Wk : Wv;
    bf16x8 v;
#pragma unroll
    for (int j = 0; j < 8; ++j)
        v[j] = f2bf(W[(size_t)(ks * 32 + (l >> 4) * 8 + j) * HD + n * 16 + (l & 15)]);
    *reinterpret_cast<bf16x8*>(wfrag + (size_t)idx * 8) = v;
}

// ---------------------------------------------------------------------------
// proj: grid 512, block 256 (4 waves).  Block = one 16-row tile of ALL THREE
// outputs; waves split K 4-ways (8 ks-iters each); f32x4 LDS reduction;
// wave 0 -> Q (x0.125), 1 -> K, 2 -> Vt (transposed).  x read exactly once.
// (R7-validated body.)
// ---------------------------------------------------------------------------
__global__ __launch_bounds__(256) void proj_kernel(
    const float* __restrict__ x, const short* __restrict__ wfrag,
    const float* __restrict__ bq, const float* __restrict__ bk,
    const float* __restrict__ bv,
    short* __restrict__ Qs, short* __restrict__ Kb, short* __restrict__ Vt)
{
    __shared__ __align__(16) char smem[49152 + 2304];

    const int tid  = threadIdx.x;
    const int lane = tid & 63;
    const int w    = tid >> 6;
    const int c    = lane & 15;
    const int g    = lane >> 4;
    const int r0   = blockIdx.x * 16;

    f32x4 acc[3][4] = {};
    for (int ks = w * 8; ks < w * 8 + 8; ++ks) {
        const float* xp = x + (size_t)(r0 + c) * DIM + ks * 32 + g * 8;
        float4 a0 = *reinterpret_cast<const float4*>(xp);
        float4 a1 = *reinterpret_cast<const float4*>(xp + 4);
        float av[8] = {a0.x, a0.y, a0.z, a0.w, a1.x, a1.y, a1.z, a1.w};
        bf16x8 af;
#pragma unroll
        for (int j = 0; j < 8; ++j) af[j] = f2bf_fast(av[j]);
#pragma unroll
        for (int which = 0; which < 3; ++which)
#pragma unroll
            for (int n = 0; n < 4; ++n) {
                bf16x8 bfr = *reinterpret_cast<const bf16x8*>(
                    wfrag + ((size_t)((which * 32 + ks) * 4 + n) * 64 + lane) * 8);
                acc[which][n] = MFMA16(af, bfr, acc[which][n]);
            }
    }

    f32x4* red = (f32x4*)smem;   // [chunk 12][wave 4][lane 64]
#pragma unroll
    for (int which = 0; which < 3; ++which)
#pragma unroll
        for (int n = 0; n < 4; ++n)
            red[((which * 4 + n) * 4 + w) * 64 + lane] = acc[which][n];
    __syncthreads();

    if (w < 3) {
        const float* __restrict__ bias = (w == 0) ? bq : (w == 1) ? bk : bv;
        f32x4 sum[4];
#pragma unroll
        for (int n = 0; n < 4; ++n) {
            sum[n] = red[((w * 4 + n) * 4 + 0) * 64 + lane];
#pragma unroll
            for (int s = 1; s < 4; ++s)
                sum[n] += red[((w * 4 + n) * 4 + s) * 64 + lane];
        }
        if (w < 2) {
            short* __restrict__ o = (w == 0) ? Qs : Kb;
            const float sc = (w == 0) ? 0.125f : 1.0f;
#pragma unroll
            for (int n = 0; n < 4; ++n) {
                const float bb = bias[n * 16 + c];
#pragma unroll
                for (int i = 0; i < 4; ++i)
                    o[(size_t)(r0 + g * 4 + i) * HD + n * 16 + c] =
                        f2bf((sum[n][i] + bb) * sc);
            }
        } else {
            short* ts = (short*)(smem + 49152);    // [16][72]
#pragma unroll
            for (int n = 0; n < 4; ++n) {
                const float bb = bias[n * 16 + c];
#pragma unroll
                for (int i = 0; i < 4; ++i)
                    ts[(g * 4 + i) * 72 + n * 16 + c] = f2bf(sum[n][i] + bb);
            }
            // same-wave LDS RAW: compiler inserts lgkmcnt wait
            bf16x8 o0, o1;
#pragma unroll
            for (int e = 0; e < 8; ++e) o0[e] = ts[e * 72 + lane];
#pragma unroll
            for (int e = 0; e < 8; ++e) o1[e] = ts[(8 + e) * 72 + lane];
            const int b  = r0 >> 11;
            const int sb = r0 & (SEQ - 1);
            short* dst = Vt + (((size_t)(b * 64 + lane)) << 11) + sb;
            *reinterpret_cast<bf16x8*>(dst)     = o0;
            *reinterpret_cast<bf16x8*>(dst + 8) = o1;
        }
    }
}

// ---------------------------------------------------------------------------
// One key-tile step of online-softmax flash attention (R2-validated body).
// Static references keep all state in registers (no runtime indexing).
// ---------------------------------------------------------------------------
__device__ __forceinline__ void tile_step(
    const short* __restrict__ Kb, const short* __restrict__ Vt,
    size_t krow0, int batch, int t, int tlast, int qbase,
    int c, int g, short* P, bf16x8 qf0, bf16x8 qf1,
    f32x4 (&O)[4], float (&m_i)[4], float (&l_i)[4])
{
    const int key0 = t * 64;
    bf16x8 kf[4][2];
#pragma unroll
    for (int n = 0; n < 4; ++n)
#pragma unroll
        for (int st = 0; st < 2; ++st)
            kf[n][st] = *reinterpret_cast<const bf16x8*>(
                Kb + (krow0 + key0 + n * 16 + c) * HD + st * 32 + g * 8);
    f32x4 S[4] = {};
#pragma unroll
    for (int n = 0; n < 4; ++n) {
        S[n] = MFMA16(qf0, kf[n][0], S[n]);
        S[n] = MFMA16(qf1, kf[n][1], S[n]);
    }
    if (t == tlast) {
#pragma unroll
        for (int n = 0; n < 4; ++n)
#pragma unroll
            for (int i = 0; i < 4; ++i)
                if (key0 + n * 16 + c > qbase + g * 4 + i)
                    S[n][i] = -__builtin_inff();
    }
    float mx[4], corr[4], rs[4];
#pragma unroll
    for (int i = 0; i < 4; ++i)
        mx[i] = fmaxf(fmaxf(S[0][i], S[1][i]), fmaxf(S[2][i], S[3][i]));
#pragma unroll
    for (int off = 1; off <= 8; off <<= 1)
#pragma unroll
        for (int i = 0; i < 4; ++i)
            mx[i] = fmaxf(mx[i], __shfl_xor(mx[i], off, 64));
#pragma unroll
    for (int i = 0; i < 4; ++i) {
        const float mn = fmaxf(m_i[i], mx[i]);
        corr[i] = __expf(m_i[i] - mn);   // exp(-inf)=0 on first tile
        m_i[i] = mn;
        rs[i] = 0.f;
    }
#pragma unroll
    for (int n = 0; n < 4; ++n)
#pragma unroll
        for (int i = 0; i < 4; ++i) {
            const float p = __expf(S[n][i] - m_i[i]);
            S[n][i] = p;
            rs[i] += p;
        }
#pragma unroll
    for (int off = 1; off <= 8; off <<= 1)
#pragma unroll
        for (int i = 0; i < 4; ++i)
            rs[i] += __shfl_xor(rs[i], off, 64);
#pragma unroll
    for (int i = 0; i < 4; ++i) l_i[i] = l_i[i] * corr[i] + rs[i];
#pragma unroll
    for (int n = 0; n < 4; ++n)
#pragma unroll
        for (int i = 0; i < 4; ++i) O[n][i] *= corr[i];
#pragma unroll
    for (int n = 0; n < 4; ++n)
#pragma unroll
        for (int i = 0; i < 4; ++i)
            P[(g * 4 + i) * 72 + n * 16 + c] = f2bf_fast(S[n][i]);
    // same-wave LDS RAW: compiler inserts lgkmcnt wait
#pragma unroll
    for (int st = 0; st < 2; ++st) {
        bf16x8 pf = *reinterpret_cast<const bf16x8*>(&P[c * 72 + st * 32 + g * 8]);
#pragma unroll
        for (int n = 0; n < 4; ++n) {
            bf16x8 vf = *reinterpret_cast<const bf16x8*>(
                Vt + (((size_t)(batch * 64 + n * 16 + c)) << 11) + key0 + st * 32 + g * 8);
            O[n] = MFMA16(pf, vf, O[n]);
        }
    }
}

// ===========================================================================
// attn_fused: balanced single-pass.  Block = q-tile pair (p, 127-p) of one
// batch: the pair's causal work is EXACTLY 33 key-tiles for every p.
// 4 waves take tiles round-robin from the concatenated [A|B] list, each
// keeping two online-softmax states; block-local LDS combine (syncthreads
// only -- no atomics, no fences, no global partials).  256 blocks = 1/CU.
// ===========================================================================
__global__ __launch_bounds__(256) void attn_fused_kernel(
    const short* __restrict__ Qs, const short* __restrict__ Kb,
    const short* __restrict__ Vt, float* __restrict__ out)
{
    __shared__ float  Ost[4][2][16][68];   // 34.8 KB (pad 68: 2-way = free)
    __shared__ float2 mlst[4][2][16];      // 1 KB
    __shared__ short  Pw[4][16 * 72];      // 9.2 KB

    const int tid  = threadIdx.x;
    const int lane = tid & 63;
    const int w    = tid >> 6;
    const int c    = lane & 15;
    const int g    = lane >> 4;

    const int batch = blockIdx.x >> 6;     // 0..3
    const int p     = blockIdx.x & 63;     // pair id
    const int qlocA = p;
    const int qlocB = 127 - p;
    const int ntA   = (qlocA >> 2) + 1;    // 1..16
    const int ntB   = (qlocB >> 2) + 1;    // 17..32   (ntA+ntB == 33)
    const int qbA   = batch * 128 + qlocA;
    const int qbB   = batch * 128 + qlocB;

    bf16x8 qfA0 = *reinterpret_cast<const bf16x8*>(Qs + (size_t)(qbA * 16 + c) * HD + g * 8);
    bf16x8 qfA1 = *reinterpret_cast<const bf16x8*>(Qs + (size_t)(qbA * 16 + c) * HD + 32 + g * 8);
    bf16x8 qfB0 = *reinterpret_cast<const bf16x8*>(Qs + (size_t)(qbB * 16 + c) * HD + g * 8);
    bf16x8 qfB1 = *reinterpret_cast<const bf16x8*>(Qs + (size_t)(qbB * 16 + c) * HD + 32 + g * 8);

    f32x4 OA[4] = {}, OB[4] = {};
    float mA[4], lA[4], mB[4], lB[4];
#pragma unroll
    for (int i = 0; i < 4; ++i) {
        mA[i] = -__builtin_inff(); lA[i] = 0.f;
        mB[i] = -__builtin_inff(); lB[i] = 0.f;
    }

    short* P = Pw[w];
    const size_t krow0 = (size_t)batch * SEQ;

    for (int idx = w; idx < 33; idx += 4) {
        if (idx < ntA) {
            tile_step(Kb, Vt, krow0, batch, idx, ntA - 1, qlocA * 16,
                      c, g, P, qfA0, qfA1, OA, mA, lA);
        } else {
            tile_step(Kb, Vt, krow0, batch, idx - ntA, ntB - 1, qlocB * 16,
                      c, g, P, qfB0, qfB1, OB, mB, lB);
        }
    }

    // ---- publish per-wave states ----
#pragma unroll
    for (int n = 0; n < 4; ++n)
#pragma unroll
        for (int i = 0; i < 4; ++i) {
            Ost[w][0][g * 4 + i][n * 16 + c] = OA[n][i];
            Ost[w][1][g * 4 + i][n * 16 + c] = OB[n][i];
        }
    if (c == 0) {
#pragma unroll
        for (int i = 0; i < 4; ++i) {
            mlst[w][0][g * 4 + i] = make_float2(mA[i], lA[i]);
            mlst[w][1][g * 4 + i] = make_float2(mB[i], lB[i]);
        }
    }
    __syncthreads();

    // ---- block-local combine: wave w -> state w>>1, rows (w&1)*8..+8 ----
    {
        const int s  = w >> 1;
        const int qb = (w >> 1) ? qbB : qbA;
#pragma unroll
        for (int ri = 0; ri < 8; ++ri) {
            const int row = (w & 1) * 8 + ri;
            float M = -__builtin_inff();
#pragma unroll
            for (int wv = 0; wv < 4; ++wv)
                M = fmaxf(M, mlst[wv][s][row].x);
            float l = 0.f, o = 0.f;
#pragma unroll
            for (int wv = 0; wv < 4; ++wv) {
                const float2 ml = mlst[wv][s][row];
                const float wgt = __expf(ml.x - M);   // exp(-inf)=0: empty state
                l += wgt * ml.y;
                o += wgt * Ost[wv][s][row][lane];
            }
            out[(size_t)(qb * 16 + row) * HD + lane] = o / l;
        }
    }
}

// ---------------------------------------------------------------------------
extern "C" void kernel_launch(void* const* d_in, const int* in_sizes, int n_in,
                              void* d_out, int out_size, void* d_ws, size_t ws_size,
                              hipStream_t stream)
{
    (void)in_sizes; (void)n_in; (void)out_size; (void)ws_size;
    const float* x  = (const float*)d_in[0];
    const float* Wq = (const float*)d_in[1];
    const float* bq = (const float*)d_in[2];
    const float* Wk = (const float*)d_in[3];
    const float* bk = (const float*)d_in[4];
    const float* Wv = (const float*)d_in[5];
    const float* bv = (const float*)d_in[6];
    float* out = (float*)d_out;

    char* ws = (char*)d_ws;
    short* Qs    = (short*)(ws);                  // 1 MB  [8192][64] bf16 (q/8)
    short* Kb    = (short*)(ws + (1u << 20));     // 1 MB
    short* Vt    = (short*)(ws + (2u << 20));     // 1 MB  [4][64][2048]
    short* wfrag = (short*)(ws + (3u << 20));     // 384 KB

    wprep_kernel<<<96, 256, 0, stream>>>(Wq, Wk, Wv, wfrag);
    proj_kernel<<<512, 256, 0, stream>>>(x, wfrag, bq, bk, bv, Qs, Kb, Vt);
    attn_fused_kernel<<<256, 256, 0, stream>>>(Qs, Kb, Vt, out);
}